// Round 11
// baseline (160.300 us; speedup 1.0000x reference)
//
#include <hip/hip_runtime.h>

typedef _Float16 half8 __attribute__((ext_vector_type(8)));
typedef _Float16 half4v __attribute__((ext_vector_type(4)));
typedef float floatx4 __attribute__((ext_vector_type(4)));
typedef unsigned uint4v __attribute__((ext_vector_type(4)));
typedef unsigned uint2v __attribute__((ext_vector_type(2)));

#define KDIM 512

__device__ __forceinline__ void gll16(const void* g, void* l) {
  __builtin_amdgcn_global_load_lds((const __attribute__((address_space(1))) void*)g,
                                   (__attribute__((address_space(3))) void*)l, 16, 0, 0);
}

__device__ __forceinline__ unsigned pack2(float a, float b) {
  return __builtin_bit_cast(unsigned, __builtin_amdgcn_cvt_pkrtz(a, b));
}

// ---------------- conversion: f32 -> f16 (x + weights) — R9 proven ----------------
__global__ void cvt_all(const float* __restrict__ x, const float* __restrict__ wq,
                        const float* __restrict__ wp, _Float16* __restrict__ xh,
                        _Float16* __restrict__ wqh, _Float16* __restrict__ wph) {
  long stride = (long)gridDim.x * blockDim.x;
  long t0 = (long)blockIdx.x * blockDim.x + threadIdx.x;
  for (long i = t0; i < 17301504L/4; i += stride) {
    float4 v = ((const float4*)x)[i];
    half4v h; h[0]=(_Float16)v.x; h[1]=(_Float16)v.y; h[2]=(_Float16)v.z; h[3]=(_Float16)v.w;
    ((half4v*)xh)[i] = h;
  }
  for (long i = t0; i < 786432L/4; i += stride) {
    float4 v = ((const float4*)wq)[i];
    half4v h; h[0]=(_Float16)v.x; h[1]=(_Float16)v.y; h[2]=(_Float16)v.z; h[3]=(_Float16)v.w;
    ((half4v*)wqh)[i] = h;
  }
  for (long i = t0; i < 262144L/4; i += stride) {
    float4 v = ((const float4*)wp)[i];
    half4v h; h[0]=(_Float16)v.x; h[1]=(_Float16)v.y; h[2]=(_Float16)v.z; h[3]=(_Float16)v.w;
    ((half4v*)wph)[i] = h;
  }
}

// ---- GEMM: 128x256 block, R9-proven 2-barrier gll16 skeleton, wave-tile 64x128 ----
// C[M][NN] = A[M][512] * Bw[NN][512]^T + bias. Grid = 8 * (264/8) * (NN/256).
template<int NN, bool OUTF16>
__global__ __launch_bounds__(256, 2) void gemm_bt(const _Float16* __restrict__ A,
    const _Float16* __restrict__ Bw, const float* __restrict__ bias,
    void* __restrict__ Cout) {
  __shared__ __attribute__((aligned(16))) _Float16 As[128 * 64];   // 16KB
  __shared__ __attribute__((aligned(16))) _Float16 Bs[256 * 64];   // 32KB
  const int ntile = NN / 256;
  int bid = blockIdx.x;
  int xcd = bid & 7, idx = bid >> 3;
  int mt = (idx / ntile) * 8 + xcd;             // 264%8==0 -> bijective
  int nt = idx % ntile;                         // A-panel sharers on one XCD
  int tid = threadIdx.x;
  int lane = tid & 63;
  int w = tid >> 6, wr = w >> 1, wc = w & 1;    // 2M x 2N waves, wave tile 64x128
  int g = lane >> 4, c = lane & 15;
  long arow0 = (long)mt * 128;
  int bcol0 = nt * 256;
  floatx4 acc[4][8];
#pragma unroll
  for (int i = 0; i < 4; i++)
#pragma unroll
    for (int j = 0; j < 8; j++) acc[i][j] = (floatx4)0.0f;

  int wbase = tid & ~63;
  for (int kt = 0; kt < KDIM / 64; ++kt) {
    if (kt) __syncthreads();
    int k0 = kt * 64;
    // A: 128x64 f16, 4 gll16/thread
#pragma unroll
    for (int j = 0; j < 4; ++j) {
      int idx4 = j * 256 + tid;
      int row = idx4 >> 3;
      int sc = (idx4 & 7) ^ (row & 7);          // inverse-swizzled source chunk
      gll16(A + ((arow0 + row) * KDIM + k0 + sc * 8), (char*)As + (j * 256 + wbase) * 16);
    }
    // B: 256x64 f16, 8 gll16/thread
#pragma unroll
    for (int j = 0; j < 8; ++j) {
      int idx4 = j * 256 + tid;
      int row = idx4 >> 3;
      int sc = (idx4 & 7) ^ (row & 7);
      gll16(Bw + ((long)(bcol0 + row) * KDIM + k0 + sc * 8), (char*)Bs + (j * 256 + wbase) * 16);
    }
    __syncthreads();
#pragma unroll
    for (int ks = 0; ks < 2; ++ks) {
      half8 af[4], bf[8];
      int cb = ks * 64 + g * 16;
#pragma unroll
      for (int i = 0; i < 4; ++i) {
        int ra = wr * 64 + i * 16 + c;
        af[i] = *(const half8*)((const char*)As + ra * 128 + (cb ^ ((ra & 7) << 4)));
      }
#pragma unroll
      for (int ni = 0; ni < 8; ++ni) {
        int rb = wc * 128 + ni * 16 + c;
        bf[ni] = *(const half8*)((const char*)Bs + rb * 128 + (cb ^ ((rb & 7) << 4)));
      }
#pragma unroll
      for (int mi = 0; mi < 4; mi++)
#pragma unroll
        for (int ni = 0; ni < 8; ni++)
          acc[mi][ni] = __builtin_amdgcn_mfma_f32_16x16x32_f16(af[mi], bf[ni], acc[mi][ni], 0, 0, 0);
    }
  }
  long crow0 = arow0 + wr * 64;
  int ccol0 = bcol0 + wc * 128;
#pragma unroll
  for (int mi = 0; mi < 4; mi++) {
#pragma unroll
    for (int ni = 0; ni < 8; ni++) {
      int col = ccol0 + ni * 16 + c;
      float bv = bias[col];
#pragma unroll
      for (int j = 0; j < 4; j++) {
        long r = crow0 + mi * 16 + g * 4 + j;
        float v = acc[mi][ni][j] + bv;
        if (OUTF16) ((_Float16*)Cout)[r * NN + col] = (_Float16)v;
        else        ((float*)Cout)[r * NN + col] = v;
      }
    }
  }
}

// ---------------- fused block attention (transposed-score, in-register P) ----------------
__global__ __launch_bounds__(256, 4) void attn_mid(const _Float16* __restrict__ qkv,
    const int* __restrict__ amask, const float* __restrict__ ef,
    const float* __restrict__ Wg, const float* __restrict__ bg,
    _Float16* __restrict__ aout) {
  __shared__ __attribute__((aligned(16))) half4v efT[48][42];   // [k][q], zero-padded
  __shared__ __attribute__((aligned(16))) _Float16 outb[4][33][88];
  __shared__ unsigned long long mrow[48];
  int blk = blockIdx.x;          // b*256 + nb
  int nb = blk & 255;
  long R0 = (long)blk * 33;
  int tid = threadIdx.x;
  int lane = tid & 63, w = tid >> 6;
  int g = lane >> 4, c = lane & 15;

  if (tid < 48) {
    unsigned long long bits = 0;
    if (tid < 33) {
      const int* mp = amask + ((long)nb * 33 + tid) * 33;
      for (int k = 0; k < 33; k++) if (mp[k]) bits |= (1ull << k);
    }
    mrow[tid] = bits;
  }
  for (int u = tid; u < 48 * 42; u += 256) {
    int k = u / 42, q = u - k * 42;
    half4v hv; hv[0] = (_Float16)0.f; hv[1] = (_Float16)0.f; hv[2] = (_Float16)0.f; hv[3] = (_Float16)0.f;
    if (q < 33 && k < 33) {
      if (q == k) hv[3] = (_Float16)1.0f;
      else {
        float4 e4 = *(const float4*)(ef + (((long)nb * 33 + q) * 33 + k) * 4);
        hv[0] = (_Float16)e4.x; hv[1] = (_Float16)e4.y; hv[2] = (_Float16)e4.z; hv[3] = (_Float16)e4.w;
      }
    }
    efT[k][q] = hv;
  }
  __syncthreads();

  for (int hh = 0; hh < 2; ++hh) {
    int h = w + 4 * hh;
    float wg0 = Wg[h * 4 + 0], wg1 = Wg[h * 4 + 1], wg2 = Wg[h * 4 + 2], wg3 = Wg[h * 4 + 3];
    float bgh = bg[h];
    half8 qf[3][2], kf[3][2];
#pragma unroll
    for (int t3 = 0; t3 < 3; ++t3) {
      int t = t3 * 16 + c;
      long tr = R0 + (t < 33 ? t : 0);
#pragma unroll
      for (int ks = 0; ks < 2; ++ks) {
        int d0 = ks * 32 + g * 8;
        qf[t3][ks] = *(const half8*)(qkv + tr * 1536 + h * 64 + d0);
        kf[t3][ks] = *(const half8*)(qkv + tr * 1536 + 512 + h * 64 + d0);
      }
    }
    floatx4 s[3][3];
#pragma unroll
    for (int kt = 0; kt < 3; kt++)
#pragma unroll
      for (int qt = 0; qt < 3; qt++) s[kt][qt] = (floatx4)0.0f;
#pragma unroll
    for (int ks = 0; ks < 2; ++ks)
#pragma unroll
      for (int kt = 0; kt < 3; kt++)
#pragma unroll
        for (int qt = 0; qt < 3; qt++)
          s[kt][qt] = __builtin_amdgcn_mfma_f32_16x16x32_f16(kf[kt][ks], qf[qt][ks], s[kt][qt], 0, 0, 0);

    unsigned pk[2][3][2];
    float cw32[3];
#pragma unroll
    for (int qt = 0; qt < 3; qt++) {
      int q = qt * 16 + c;
      unsigned long long mb = mrow[q];
      float sv[3][4];
#pragma unroll
      for (int kt = 0; kt < 3; kt++)
#pragma unroll
        for (int j = 0; j < 4; j++) {
          int k = kt * 16 + 4 * g + j;
          float e3 = (float)efT[k][q][3];
          bool mk = (mb >> k) & 1;
          sv[kt][j] = mk ? s[kt][qt][j] * 0.125f + e3 : -1e30f;
        }
      float m = sv[0][0];
#pragma unroll
      for (int kt = 0; kt < 3; kt++)
#pragma unroll
        for (int j = 0; j < 4; j++) m = fmaxf(m, sv[kt][j]);
      m = fmaxf(m, __shfl_xor(m, 16, 64));
      m = fmaxf(m, __shfl_xor(m, 32, 64));
      float p[3][4], sum = 0.f;
#pragma unroll
      for (int kt = 0; kt < 3; kt++)
#pragma unroll
        for (int j = 0; j < 4; j++) { p[kt][j] = __expf(sv[kt][j] - m); sum += p[kt][j]; }
      sum += __shfl_xor(sum, 16, 64);
      sum += __shfl_xor(sum, 32, 64);
      float inv = __builtin_amdgcn_rcpf(sum);
      float cw[3][4];
#pragma unroll
      for (int kt = 0; kt < 3; kt++)
#pragma unroll
        for (int j = 0; j < 4; j++) {
          int k = kt * 16 + 4 * g + j;
          bool mk = (mb >> k) & 1;
          half4v e = efT[k][q];
          float gate = (float)e[0] * wg0 + (float)e[1] * wg1 + (float)e[2] * wg2 + (float)e[3] * wg3 + bgh;
          cw[kt][j] = mk ? p[kt][j] * inv + gate : 0.0f;
        }
#pragma unroll
      for (int kt = 0; kt < 2; kt++)
#pragma unroll
        for (int jp = 0; jp < 2; jp++) pk[kt][qt][jp] = pack2(cw[kt][2 * jp], cw[kt][2 * jp + 1]);
      cw32[qt] = cw[2][0];
    }

    half8 pb[3];
#pragma unroll
    for (int qt = 0; qt < 3; qt++) {
      uint4v d;
#pragma unroll
      for (int w2 = 0; w2 < 4; w2++) {
        int srcl = (((g & 1) * 2 + (w2 >> 1)) << 4) | c;
        unsigned v0 = (unsigned)__shfl((int)pk[0][qt][w2 & 1], srcl, 64);
        unsigned v1 = (unsigned)__shfl((int)pk[1][qt][w2 & 1], srcl, 64);
        d[w2] = (g >> 1) ? v1 : v0;
      }
      pb[qt] = __builtin_bit_cast(half8, d);
    }

    floatx4 o[4][3];
#pragma unroll
    for (int dt = 0; dt < 4; dt++)
#pragma unroll
      for (int qt = 0; qt < 3; qt++) o[dt][qt] = (floatx4)0.0f;
#pragma unroll
    for (int dh = 0; dh < 2; dh++) {
      half8 vf[2];
#pragma unroll
      for (int di = 0; di < 2; di++) {
        int dt = dh * 2 + di;
        half8 v;
#pragma unroll
        for (int e = 0; e < 8; e++)
          v[e] = qkv[(R0 + g * 8 + e) * 1536 + 1024 + h * 64 + dt * 16 + c];
        vf[di] = v;
      }
#pragma unroll
      for (int di = 0; di < 2; di++)
#pragma unroll
        for (int qt = 0; qt < 3; qt++)
          o[dh * 2 + di][qt] = __builtin_amdgcn_mfma_f32_16x16x32_f16(vf[di], pb[qt], o[dh * 2 + di][qt], 0, 0, 0);
    }
    float p32[3];
#pragma unroll
    for (int qt = 0; qt < 3; qt++) p32[qt] = __shfl(cw32[qt], c, 64);
#pragma unroll
    for (int dt = 0; dt < 4; dt++) {
      half4v v32 = *(const half4v*)(qkv + (R0 + 32) * 1536 + 1024 + h * 64 + dt * 16 + 4 * g);
#pragma unroll
      for (int qt = 0; qt < 3; qt++)
#pragma unroll
        for (int j = 0; j < 4; j++) o[dt][qt][j] += (float)v32[j] * p32[qt];
    }

#pragma unroll
    for (int qt = 0; qt < 3; qt++) {
      int q = qt * 16 + c;
      if (q < 33) {
#pragma unroll
        for (int dt = 0; dt < 4; dt++) {
          uint2v uu;
          uu[0] = pack2(o[dt][qt][0], o[dt][qt][1]);
          uu[1] = pack2(o[dt][qt][2], o[dt][qt][3]);
          *(uint2v*)&outb[w][q][dt * 16 + 4 * g] = uu;
        }
      }
    }
#pragma unroll
    for (int r0 = 0; r0 < 5; ++r0) {
      int q = r0 * 8 + (lane >> 3);
      if (q < 33) {
        half8 vv = *(const half8*)&outb[w][q][(lane & 7) * 8];
        *(half8*)(aout + (R0 + q) * 512 + h * 64 + (lane & 7) * 8) = vv;
      }
    }
  }
}

extern "C" void kernel_launch(void* const* d_in, const int* in_sizes, int n_in,
                              void* d_out, int out_size, void* d_ws, size_t ws_size,
                              hipStream_t stream) {
  const float* x  = (const float*)d_in[0];
  const int*   am = (const int*)d_in[1];
  const float* ef = (const float*)d_in[2];
  const float* Wq = (const float*)d_in[3];
  const float* bq = (const float*)d_in[4];
  const float* Wp = (const float*)d_in[5];
  const float* bp = (const float*)d_in[6];
  const float* Wg = (const float*)d_in[7];
  const float* bg = (const float*)d_in[8];
  char* ws = (char*)d_ws;
  _Float16* xh   = (_Float16*)(ws);
  _Float16* wqh  = (_Float16*)(ws + 34603008L);
  _Float16* wph  = (_Float16*)(ws + 36175872L);
  _Float16* qkv  = (_Float16*)(ws + 36700160L);
  _Float16* aout = (_Float16*)(ws + 140509184L);

  hipLaunchKernelGGL(cvt_all, dim3(2048), dim3(256), 0, stream, x, Wq, Wp, xh, wqh, wph);
  hipLaunchKernelGGL((gemm_bt<1536, true>), dim3(1584), dim3(256), 0, stream, xh, wqh, bq, (void*)qkv);
  hipLaunchKernelGGL(attn_mid, dim3(1024), dim3(256), 0, stream, qkv, am, ef, Wg, bg, aout);
  hipLaunchKernelGGL((gemm_bt<512, false>), dim3(528), dim3(256), 0, stream, aout, wph, bp, (float*)d_out);
}

// Round 12
// 143.752 us; speedup vs baseline: 1.1151x; 1.1151x over previous
//
#include <hip/hip_runtime.h>

typedef _Float16 half8 __attribute__((ext_vector_type(8)));
typedef _Float16 half4v __attribute__((ext_vector_type(4)));
typedef float floatx4 __attribute__((ext_vector_type(4)));
typedef unsigned uint4v __attribute__((ext_vector_type(4)));
typedef unsigned uint2v __attribute__((ext_vector_type(2)));

#define KDIM 512

__device__ __forceinline__ void gll16(const _Float16* g, void* l) {
  __builtin_amdgcn_global_load_lds((const __attribute__((address_space(1))) void*)g,
                                   (__attribute__((address_space(3))) void*)l, 16, 0, 0);
}

__device__ __forceinline__ unsigned pack2(float a, float b) {
  return __builtin_bit_cast(unsigned, __builtin_amdgcn_cvt_pkrtz(a, b));
}

// ---------------- conversion: f32 -> f16 (x + weights) ----------------
__global__ void cvt_all(const float* __restrict__ x, const float* __restrict__ wq,
                        const float* __restrict__ wp, _Float16* __restrict__ xh,
                        _Float16* __restrict__ wqh, _Float16* __restrict__ wph) {
  long stride = (long)gridDim.x * blockDim.x;
  long t0 = (long)blockIdx.x * blockDim.x + threadIdx.x;
  for (long i = t0; i < 17301504L/4; i += stride) {
    float4 v = ((const float4*)x)[i];
    half4v h; h[0]=(_Float16)v.x; h[1]=(_Float16)v.y; h[2]=(_Float16)v.z; h[3]=(_Float16)v.w;
    ((half4v*)xh)[i] = h;
  }
  for (long i = t0; i < 786432L/4; i += stride) {
    float4 v = ((const float4*)wq)[i];
    half4v h; h[0]=(_Float16)v.x; h[1]=(_Float16)v.y; h[2]=(_Float16)v.z; h[3]=(_Float16)v.w;
    ((half4v*)wqh)[i] = h;
  }
  for (long i = t0; i < 262144L/4; i += stride) {
    float4 v = ((const float4*)wp)[i];
    half4v h; h[0]=(_Float16)v.x; h[1]=(_Float16)v.y; h[2]=(_Float16)v.z; h[3]=(_Float16)v.w;
    ((half4v*)wph)[i] = h;
  }
}

// ---- GEMM (R3-proven 128x128 2-barrier loop) + XCD-chunked swizzle ----
// C[M][NN] = A[M][512] * Bw[NN][512]^T + bias. Grid must be 8*(264/8)*ntile.
template<int NN, bool OUTF16>
__global__ __launch_bounds__(256, 2) void gemm_bt(const _Float16* __restrict__ A,
    const _Float16* __restrict__ Bw, const float* __restrict__ bias,
    void* __restrict__ Cout) {
  __shared__ __attribute__((aligned(16))) _Float16 As[128*64];
  __shared__ __attribute__((aligned(16))) _Float16 Bs[128*64];
  const int ntile = NN / 128;
  int bid = blockIdx.x;
  int xcd = bid & 7, idx = bid >> 3;
  int mt = (idx / ntile) * 8 + xcd;             // 264%8==0 -> bijective
  int nt = idx % ntile;                         // panel-sharers land on one XCD
  int tid = threadIdx.x;
  int lane = tid & 63;
  int w = tid >> 6, wr = w >> 1, wc = w & 1;
  int g = lane >> 4, c = lane & 15;
  long arow0 = (long)mt * 128;
  int bcol0 = nt * 128;
  floatx4 acc[4][4];
#pragma unroll
  for (int i = 0; i < 4; i++)
#pragma unroll
    for (int j = 0; j < 4; j++) acc[i][j] = (floatx4)0.0f;

  int wbase = tid & ~63;
  for (int kt = 0; kt < KDIM / 64; ++kt) {
    if (kt) __syncthreads();
    int k0 = kt * 64;
#pragma unroll
    for (int j = 0; j < 4; ++j) {
      int idx4 = j * 256 + tid;
      int row = idx4 >> 3;
      int sc = (idx4 & 7) ^ (row & 7);          // inverse-swizzled source chunk
      gll16(A + ((arow0 + row) * KDIM + k0 + sc * 8), (char*)As + (j * 256 + wbase) * 16);
      gll16(Bw + ((long)(bcol0 + row) * KDIM + k0 + sc * 8), (char*)Bs + (j * 256 + wbase) * 16);
    }
    __syncthreads();
#pragma unroll
    for (int ks = 0; ks < 2; ++ks) {
      half8 af[4], bf[4];
      int cb = ks * 64 + g * 16;
#pragma unroll
      for (int i = 0; i < 4; ++i) {
        int ra = wr * 64 + i * 16 + c;
        af[i] = *(const half8*)((const char*)As + ra * 128 + (cb ^ ((ra & 7) << 4)));
        int rb = wc * 64 + i * 16 + c;
        bf[i] = *(const half8*)((const char*)Bs + rb * 128 + (cb ^ ((rb & 7) << 4)));
      }
#pragma unroll
      for (int mi = 0; mi < 4; mi++)
#pragma unroll
        for (int ni = 0; ni < 4; ni++)
          acc[mi][ni] = __builtin_amdgcn_mfma_f32_16x16x32_f16(af[mi], bf[ni], acc[mi][ni], 0, 0, 0);
    }
  }
  long crow0 = arow0 + wr * 64;
  int ccol0 = bcol0 + wc * 64;
#pragma unroll
  for (int mi = 0; mi < 4; mi++) {
#pragma unroll
    for (int ni = 0; ni < 4; ni++) {
      int col = ccol0 + ni * 16 + c;
      float bv = bias[col];
#pragma unroll
      for (int j = 0; j < 4; j++) {
        long r = crow0 + mi * 16 + g * 4 + j;
        float v = acc[mi][ni][j] + bv;
        if (OUTF16) ((_Float16*)Cout)[r * NN + col] = (_Float16)v;
        else        ((float*)Cout)[r * NN + col] = v;
      }
    }
  }
}

// ---------------- fused block attention (transposed-score, in-register P) ----------------
__global__ __launch_bounds__(256, 4) void attn_mid(const _Float16* __restrict__ qkv,
    const int* __restrict__ amask, const float* __restrict__ ef,
    const float* __restrict__ Wg, const float* __restrict__ bg,
    _Float16* __restrict__ aout) {
  __shared__ __attribute__((aligned(16))) half4v efT[48][42];   // [k][q], zero-padded
  __shared__ __attribute__((aligned(16))) _Float16 outb[4][33][88];
  __shared__ unsigned long long mrow[48];
  int blk = blockIdx.x;          // b*256 + nb
  int nb = blk & 255;
  long R0 = (long)blk * 33;
  int tid = threadIdx.x;
  int lane = tid & 63, w = tid >> 6;
  int g = lane >> 4, c = lane & 15;

  if (tid < 48) {
    unsigned long long bits = 0;
    if (tid < 33) {
      const int* mp = amask + ((long)nb * 33 + tid) * 33;
      for (int k = 0; k < 33; k++) if (mp[k]) bits |= (1ull << k);
    }
    mrow[tid] = bits;
  }
  for (int u = tid; u < 48 * 42; u += 256) {
    int k = u / 42, q = u - k * 42;
    half4v hv; hv[0] = (_Float16)0.f; hv[1] = (_Float16)0.f; hv[2] = (_Float16)0.f; hv[3] = (_Float16)0.f;
    if (q < 33 && k < 33) {
      if (q == k) hv[3] = (_Float16)1.0f;
      else {
        float4 e4 = *(const float4*)(ef + (((long)nb * 33 + q) * 33 + k) * 4);
        hv[0] = (_Float16)e4.x; hv[1] = (_Float16)e4.y; hv[2] = (_Float16)e4.z; hv[3] = (_Float16)e4.w;
      }
    }
    efT[k][q] = hv;
  }
  __syncthreads();

  for (int hh = 0; hh < 2; ++hh) {
    int h = w + 4 * hh;
    float wg0 = Wg[h * 4 + 0], wg1 = Wg[h * 4 + 1], wg2 = Wg[h * 4 + 2], wg3 = Wg[h * 4 + 3];
    float bgh = bg[h];
    half8 qf[3][2], kf[3][2];
#pragma unroll
    for (int t3 = 0; t3 < 3; ++t3) {
      int t = t3 * 16 + c;
      long tr = R0 + (t < 33 ? t : 0);
#pragma unroll
      for (int ks = 0; ks < 2; ++ks) {
        int d0 = ks * 32 + g * 8;
        qf[t3][ks] = *(const half8*)(qkv + tr * 1536 + h * 64 + d0);
        kf[t3][ks] = *(const half8*)(qkv + tr * 1536 + 512 + h * 64 + d0);
      }
    }
    floatx4 s[3][3];
#pragma unroll
    for (int kt = 0; kt < 3; kt++)
#pragma unroll
      for (int qt = 0; qt < 3; qt++) s[kt][qt] = (floatx4)0.0f;
#pragma unroll
    for (int ks = 0; ks < 2; ++ks)
#pragma unroll
      for (int kt = 0; kt < 3; kt++)
#pragma unroll
        for (int qt = 0; qt < 3; qt++)
          s[kt][qt] = __builtin_amdgcn_mfma_f32_16x16x32_f16(kf[kt][ks], qf[qt][ks], s[kt][qt], 0, 0, 0);

    unsigned pk[2][3][2];
    float cw32[3];
#pragma unroll
    for (int qt = 0; qt < 3; qt++) {
      int q = qt * 16 + c;
      unsigned long long mb = mrow[q];
      float sv[3][4];
#pragma unroll
      for (int kt = 0; kt < 3; kt++)
#pragma unroll
        for (int j = 0; j < 4; j++) {
          int k = kt * 16 + 4 * g + j;
          float e3 = (float)efT[k][q][3];
          bool mk = (mb >> k) & 1;
          sv[kt][j] = mk ? s[kt][qt][j] * 0.125f + e3 : -1e30f;
        }
      float m = sv[0][0];
#pragma unroll
      for (int kt = 0; kt < 3; kt++)
#pragma unroll
        for (int j = 0; j < 4; j++) m = fmaxf(m, sv[kt][j]);
      m = fmaxf(m, __shfl_xor(m, 16, 64));
      m = fmaxf(m, __shfl_xor(m, 32, 64));
      float p[3][4], sum = 0.f;
#pragma unroll
      for (int kt = 0; kt < 3; kt++)
#pragma unroll
        for (int j = 0; j < 4; j++) { p[kt][j] = __expf(sv[kt][j] - m); sum += p[kt][j]; }
      sum += __shfl_xor(sum, 16, 64);
      sum += __shfl_xor(sum, 32, 64);
      float inv = __builtin_amdgcn_rcpf(sum);
      float cw[3][4];
#pragma unroll
      for (int kt = 0; kt < 3; kt++)
#pragma unroll
        for (int j = 0; j < 4; j++) {
          int k = kt * 16 + 4 * g + j;
          bool mk = (mb >> k) & 1;
          half4v e = efT[k][q];
          float gate = (float)e[0] * wg0 + (float)e[1] * wg1 + (float)e[2] * wg2 + (float)e[3] * wg3 + bgh;
          cw[kt][j] = mk ? p[kt][j] * inv + gate : 0.0f;
        }
#pragma unroll
      for (int kt = 0; kt < 2; kt++)
#pragma unroll
        for (int jp = 0; jp < 2; jp++) pk[kt][qt][jp] = pack2(cw[kt][2 * jp], cw[kt][2 * jp + 1]);
      cw32[qt] = cw[2][0];
    }

    half8 pb[3];
#pragma unroll
    for (int qt = 0; qt < 3; qt++) {
      uint4v d;
#pragma unroll
      for (int w2 = 0; w2 < 4; w2++) {
        int srcl = (((g & 1) * 2 + (w2 >> 1)) << 4) | c;
        unsigned v0 = (unsigned)__shfl((int)pk[0][qt][w2 & 1], srcl, 64);
        unsigned v1 = (unsigned)__shfl((int)pk[1][qt][w2 & 1], srcl, 64);
        d[w2] = (g >> 1) ? v1 : v0;
      }
      pb[qt] = __builtin_bit_cast(half8, d);
    }

    floatx4 o[4][3];
#pragma unroll
    for (int dt = 0; dt < 4; dt++)
#pragma unroll
      for (int qt = 0; qt < 3; qt++) o[dt][qt] = (floatx4)0.0f;
#pragma unroll
    for (int dh = 0; dh < 2; dh++) {
      half8 vf[2];
#pragma unroll
      for (int di = 0; di < 2; di++) {
        int dt = dh * 2 + di;
        half8 v;
#pragma unroll
        for (int e = 0; e < 8; e++)
          v[e] = qkv[(R0 + g * 8 + e) * 1536 + 1024 + h * 64 + dt * 16 + c];
        vf[di] = v;
      }
#pragma unroll
      for (int di = 0; di < 2; di++)
#pragma unroll
        for (int qt = 0; qt < 3; qt++)
          o[dh * 2 + di][qt] = __builtin_amdgcn_mfma_f32_16x16x32_f16(vf[di], pb[qt], o[dh * 2 + di][qt], 0, 0, 0);
    }
    float p32[3];
#pragma unroll
    for (int qt = 0; qt < 3; qt++) p32[qt] = __shfl(cw32[qt], c, 64);
#pragma unroll
    for (int dt = 0; dt < 4; dt++) {
      half4v v32 = *(const half4v*)(qkv + (R0 + 32) * 1536 + 1024 + h * 64 + dt * 16 + 4 * g);
#pragma unroll
      for (int qt = 0; qt < 3; qt++)
#pragma unroll
        for (int j = 0; j < 4; j++) o[dt][qt][j] += (float)v32[j] * p32[qt];
    }

#pragma unroll
    for (int qt = 0; qt < 3; qt++) {
      int q = qt * 16 + c;
      if (q < 33) {
#pragma unroll
        for (int dt = 0; dt < 4; dt++) {
          uint2v uu;
          uu[0] = pack2(o[dt][qt][0], o[dt][qt][1]);
          uu[1] = pack2(o[dt][qt][2], o[dt][qt][3]);
          *(uint2v*)&outb[w][q][dt * 16 + 4 * g] = uu;
        }
      }
    }
#pragma unroll
    for (int r0 = 0; r0 < 5; ++r0) {
      int q = r0 * 8 + (lane >> 3);
      if (q < 33) {
        half8 vv = *(const half8*)&outb[w][q][(lane & 7) * 8];
        *(half8*)(aout + (R0 + q) * 512 + h * 64 + (lane & 7) * 8) = vv;
      }
    }
  }
}

extern "C" void kernel_launch(void* const* d_in, const int* in_sizes, int n_in,
                              void* d_out, int out_size, void* d_ws, size_t ws_size,
                              hipStream_t stream) {
  const float* x  = (const float*)d_in[0];
  const int*   am = (const int*)d_in[1];
  const float* ef = (const float*)d_in[2];
  const float* Wq = (const float*)d_in[3];
  const float* bq = (const float*)d_in[4];
  const float* Wp = (const float*)d_in[5];
  const float* bp = (const float*)d_in[6];
  const float* Wg = (const float*)d_in[7];
  const float* bg = (const float*)d_in[8];
  char* ws = (char*)d_ws;
  _Float16* xh   = (_Float16*)(ws);
  _Float16* wqh  = (_Float16*)(ws + 34603008L);
  _Float16* wph  = (_Float16*)(ws + 36175872L);
  _Float16* qkv  = (_Float16*)(ws + 36700160L);
  _Float16* aout = (_Float16*)(ws + 140509184L);

  hipLaunchKernelGGL(cvt_all, dim3(2048), dim3(256), 0, stream, x, Wq, Wp, xh, wqh, wph);
  hipLaunchKernelGGL((gemm_bt<1536, true>), dim3(3168), dim3(256), 0, stream, xh, wqh, bq, (void*)qkv);
  hipLaunchKernelGGL(attn_mid, dim3(1024), dim3(256), 0, stream, qkv, am, ef, Wg, bg, aout);
  hipLaunchKernelGGL((gemm_bt<512, false>), dim3(1056), dim3(256), 0, stream, aout, wph, bp, (float*)d_out);
}